// Round 8
// baseline (5909.576 us; speedup 1.0000x reference)
//
#include <hip/hip_runtime.h>
#include <hip/hip_bf16.h>
#include <math.h>

#define VOCAB  32000
#define EMBED  256
#define HIDDEN 512
#define BATCH  32
#define MAXLEN 128
#define NBLK   256            // fused grid: 1 block per CU (co-resident by construction)
#define GBLK   250            // blocks that run the logits phase (250*128 = 32000)
#define VB     128            // v-rows per logits block

typedef __attribute__((ext_vector_type(8))) short bf16x8;          // 8 bf16 = 4 VGPR
typedef __attribute__((ext_vector_type(8))) unsigned short ushort8;
typedef __attribute__((ext_vector_type(4))) float f32x4;

// -------- workspace layout (bytes) --------
#define WS_C_OFF     0          // c[32][512] f32                    65536
#define WS_HHI_OFF   65536      // h_hi[2][32][512] bf16             65536
#define WS_HLO_OFF   131072     // h_lo[2][32][512] bf16             65536
#define WS_CAND_OFF  196608     // cand[250][32] u64                 64000
#define WS_CTR_OFF   260608     // stepctr[128][64] u32              32768
#define WS_ZERO_BYTES 293376
#define WS_WHI_OFF   294912     // W_hi[32000][512] bf16          32768000
#define WS_WLO_OFF   33062912   // W_lo[32000][512] bf16          32768000

__device__ __forceinline__ unsigned int f32_ordered_key(float f) {
    unsigned int b = __float_as_uint(f);
    return (b & 0x80000000u) ? ~b : (b | 0x80000000u);
}
__device__ __forceinline__ unsigned short f2bf(float x) {
    __hip_bfloat16 h = __float2bfloat16(x);
    return *reinterpret_cast<unsigned short*>(&h);
}
__device__ __forceinline__ float bf2f(unsigned short u) {
    __hip_bfloat16 h = *reinterpret_cast<__hip_bfloat16*>(&u);
    return __bfloat162float(h);
}

// ---------------- W_fc bf16 split precompute (once per launch) ----------------
__global__ __launch_bounds__(256) void split_w_kernel(
    const float* __restrict__ W, unsigned short* __restrict__ hi,
    unsigned short* __restrict__ lo, int n4)
{
    const int stride = gridDim.x * blockDim.x;
    for (int i = blockIdx.x * blockDim.x + threadIdx.x; i < n4; i += stride) {
        f32x4 w = ((const f32x4*)W)[i];
        ushort4 hv, lv;
        #pragma unroll
        for (int j = 0; j < 4; ++j) {
            float x = w[j];
            unsigned short hb = f2bf(x);
            ((unsigned short*)&hv)[j] = hb;
            ((unsigned short*)&lv)[j] = f2bf(x - bf2f(hb));
        }
        ((ushort4*)hi)[i] = hv;
        ((ushort4*)lo)[i] = lv;
    }
}

// ---------------- fused per-step kernel ----------------
// grid 256 x 512 threads.
// Phase A (all blocks): fold cand(t-1) -> tok.
// Phase L (all blocks): block owns j = blk*2+{0,1}; thread (b,s,jq) computes
//   1/8 of the gates dot products with direct global reads (L2-served, W rows
//   broadcast across the 32 b-lanes of each half-wave). Cell update writes
//   h_hi/h_lo[widx] (64 values per block) -> release-signal tree counter.
// Phase G (blocks 0-249): relaxed-poll counter (NO acquire in loop), one
//   fence, then round-6 logits MFMA body (swizzled h LDS, 3-pass split,
//   depth-4 W prefetch, nt stores, per-block argmax candidates).
#define MFMA(a, b, c) __builtin_amdgcn_mfma_f32_16x16x32_bf16((a), (b), (c), 0, 0, 0)
#define HPTR(arr, bb, cc) \
    ((const bf16x8*)((const char*)(arr) + ((((bb) * 1024) + (kg * 16) + (cc) * 64) ^ ((((bb) & 7)) << 4))))

__global__ __launch_bounds__(512) void fused_step_kernel(
    const float* __restrict__ embed,
    const float* __restrict__ W_ih, const float* __restrict__ W_hh,
    const float* __restrict__ b_ih, const float* __restrict__ b_hh,
    const unsigned short* __restrict__ Whi, const unsigned short* __restrict__ Wlo,
    const float* __restrict__ b_fc, float* __restrict__ out,
    unsigned short* __restrict__ h_hi, unsigned short* __restrict__ h_lo,
    float* __restrict__ c_buf, unsigned long long* __restrict__ cand,
    unsigned* __restrict__ stepctr, int t)
{
    __shared__ unsigned long long credl[16][32];                 // 4 KB
    __shared__ int tok_s[BATCH];
    __shared__ float part[8 * 32 * 2 * 4];                       // 8 KB [s][b][jq][gate]
    __shared__ float gate_s[2 * 4 * 32];                         // 1 KB [jq][gate][b]
    __shared__ unsigned short hs_hi[BATCH * HIDDEN];             // 32 KB swizzled
    __shared__ unsigned short hs_lo[BATCH * HIDDEN];             // 32 KB
    __shared__ unsigned long long red[8][BATCH];                 // 2 KB

    const int tid = threadIdx.x;
    const int blk = blockIdx.x;
    const int ridx = t & 1, widx = ridx ^ 1;
    unsigned* ctr = stepctr + (size_t)t * 64;

    // ---------- phase A: fold argmax candidates -> tok_s ----------
    if (t > 0) {
        const int rb = tid & 31, seg = tid >> 5;                 // 16 segs
        unsigned long long m = 0ull;
        for (int i = seg; i < GBLK; i += 16) {
            unsigned long long e = cand[(size_t)i * BATCH + rb];
            if (e > m) m = e;
        }
        credl[seg][rb] = m;
        __syncthreads();
        if (tid < BATCH) {
            unsigned long long mm = credl[0][tid];
            #pragma unroll
            for (int ss = 1; ss < 16; ++ss) if (credl[ss][tid] > mm) mm = credl[ss][tid];
            tok_s[tid] = (int)(~(unsigned int)(mm & 0xFFFFFFFFull));
        }
    } else {
        if (tid < BATCH) tok_s[tid] = 0;
    }
    __syncthreads();

    // ---------- phase L: gates partials, direct global reads ----------
    {
        const int b  = tid & 31;
        const int s  = (tid >> 5) & 7;      // k-eighth
        const int jq = tid >> 8;            // 0,1
        const int j  = blk * 2 + jq;

        float a0 = 0.f, a1 = 0.f, a2 = 0.f, a3 = 0.f;
        float d0 = 0.f, d1 = 0.f, d2 = 0.f, d3 = 0.f;

        {   // x part: e in [s*32, s*32+32)
            const float4* xr = (const float4*)(embed + (size_t)tok_s[b] * EMBED + s * 32);
            const float4* w0 = (const float4*)(W_ih + (size_t)j * EMBED) + s * 8;
            const float4* w1 = (const float4*)(W_ih + (size_t)(HIDDEN + j) * EMBED) + s * 8;
            const float4* w2 = (const float4*)(W_ih + (size_t)(2 * HIDDEN + j) * EMBED) + s * 8;
            const float4* w3 = (const float4*)(W_ih + (size_t)(3 * HIDDEN + j) * EMBED) + s * 8;
            #pragma unroll
            for (int g = 0; g < 8; ++g) {
                float4 xv = xr[g];
                float4 W0 = w0[g], W1 = w1[g], W2 = w2[g], W3 = w3[g];
                a0 = fmaf(W0.x, xv.x, a0); d0 = fmaf(W0.y, xv.y, d0); a0 = fmaf(W0.z, xv.z, a0); d0 = fmaf(W0.w, xv.w, d0);
                a1 = fmaf(W1.x, xv.x, a1); d1 = fmaf(W1.y, xv.y, d1); a1 = fmaf(W1.z, xv.z, a1); d1 = fmaf(W1.w, xv.w, d1);
                a2 = fmaf(W2.x, xv.x, a2); d2 = fmaf(W2.y, xv.y, d2); a2 = fmaf(W2.z, xv.z, a2); d2 = fmaf(W2.w, xv.w, d2);
                a3 = fmaf(W3.x, xv.x, a3); d3 = fmaf(W3.y, xv.y, d3); a3 = fmaf(W3.z, xv.z, a3); d3 = fmaf(W3.w, xv.w, d3);
            }
        }
        {   // h part: k in [s*64, s*64+64), reconstruct h = hi + lo
            const ushort8* hr = (const ushort8*)(h_hi + (size_t)ridx * BATCH * HIDDEN + (size_t)b * HIDDEN + s * 64);
            const ushort8* lr = (const ushort8*)(h_lo + (size_t)ridx * BATCH * HIDDEN + (size_t)b * HIDDEN + s * 64);
            const float4* w0 = (const float4*)(W_hh + (size_t)j * HIDDEN) + s * 16;
            const float4* w1 = (const float4*)(W_hh + (size_t)(HIDDEN + j) * HIDDEN) + s * 16;
            const float4* w2 = (const float4*)(W_hh + (size_t)(2 * HIDDEN + j) * HIDDEN) + s * 16;
            const float4* w3 = (const float4*)(W_hh + (size_t)(3 * HIDDEN + j) * HIDDEN) + s * 16;
            #pragma unroll
            for (int i = 0; i < 8; ++i) {
                ushort8 hv = hr[i], lv = lr[i];
                float hf[8];
                #pragma unroll
                for (int e = 0; e < 8; ++e)
                    hf[e] = bf2f((unsigned short)hv[e]) + bf2f((unsigned short)lv[e]);
                #pragma unroll
                for (int q = 0; q < 2; ++q) {
                    float4 W0 = w0[i * 2 + q], W1 = w1[i * 2 + q], W2 = w2[i * 2 + q], W3 = w3[i * 2 + q];
                    float x0 = hf[q * 4 + 0], x1 = hf[q * 4 + 1], x2 = hf[q * 4 + 2], x3 = hf[q * 4 + 3];
                    a0 = fmaf(W0.x, x0, a0); d0 = fmaf(W0.y, x1, d0); a0 = fmaf(W0.z, x2, a0); d0 = fmaf(W0.w, x3, d0);
                    a1 = fmaf(W1.x, x0, a1); d1 = fmaf(W1.y, x1, d1); a1 = fmaf(W1.z, x2, a1); d1 = fmaf(W1.w, x3, d1);
                    a2 = fmaf(W2.x, x0, a2); d2 = fmaf(W2.y, x1, d2); a2 = fmaf(W2.z, x2, a2); d2 = fmaf(W2.w, x3, d2);
                    a3 = fmaf(W3.x, x0, a3); d3 = fmaf(W3.y, x1, d3); a3 = fmaf(W3.z, x2, a3); d3 = fmaf(W3.w, x3, d3);
                }
            }
        }
        float* p = part + ((s * 32 + b) * 2 + jq) * 4;
        p[0] = a0 + d0; p[1] = a1 + d1; p[2] = a2 + d2; p[3] = a3 + d3;
    }
    __syncthreads();

    // ---------- gate reduce + nonlinearity (256 threads) ----------
    if (tid < 256) {
        const int b = tid & 31, gate = (tid >> 5) & 3, jq = tid >> 7;
        const int j = blk * 2 + jq;
        float g = 0.f;
        #pragma unroll
        for (int s = 0; s < 8; ++s) g += part[((s * 32 + b) * 2 + jq) * 4 + gate];
        g += b_ih[gate * HIDDEN + j] + b_hh[gate * HIDDEN + j];
        gate_s[(jq * 4 + gate) * 32 + b] = (gate == 2) ? tanhf(g) : 1.f / (1.f + expf(-g));
    }
    __syncthreads();

    // ---------- cell update (64 threads) ----------
    if (tid < 64) {
        const int b = tid & 31, jq = tid >> 5;
        const int j = blk * 2 + jq;
        const float iv = gate_s[(jq * 4 + 0) * 32 + b], fv = gate_s[(jq * 4 + 1) * 32 + b];
        const float gv = gate_s[(jq * 4 + 2) * 32 + b], ov = gate_s[(jq * 4 + 3) * 32 + b];
        const size_t off = (size_t)b * HIDDEN + j;
        float cn = fv * c_buf[off] + iv * gv;
        c_buf[off] = cn;
        float hv = ov * tanhf(cn);
        const size_t ho = (size_t)widx * BATCH * HIDDEN + off;
        unsigned short hh = f2bf(hv);
        h_hi[ho] = hh;
        h_lo[ho] = f2bf(hv - bf2f(hh));
    }
    __syncthreads();

    // ---------- release-signal: tree counter (32 leaves x 8 blocks) ----------
    if (tid == 0) {
        __threadfence();   // h/c writes agent-visible before signal
        const int leaf = blk >> 3;
        if (__hip_atomic_fetch_add(&ctr[leaf], 1u, __ATOMIC_RELAXED, __HIP_MEMORY_SCOPE_AGENT) == 7u)
            __hip_atomic_fetch_add(&ctr[32], 1u, __ATOMIC_RELAXED, __HIP_MEMORY_SCOPE_AGENT);
    }
    if (blk >= GBLK) return;   // blocks 250-255: LSTM contribution only

    // ---------- wait for all 256 h slices (relaxed poll, fence once) ----------
    if (tid == 0) {
        while (__hip_atomic_load(&ctr[32], __ATOMIC_RELAXED, __HIP_MEMORY_SCOPE_AGENT) != 32u)
            __builtin_amdgcn_s_sleep(8);
        __threadfence();
    }
    __syncthreads();

    // ---------- phase G: logits MFMA + nt-store + per-block argmax ----------
    {
        const unsigned short* hhi_w = h_hi + (size_t)widx * BATCH * HIDDEN;
        const unsigned short* hlo_w = h_lo + (size_t)widx * BATCH * HIDDEN;
        #pragma unroll
        for (int i = 0; i < 8; ++i) {
            int u = i * 512 + tid;
            int arr = u >> 11, b = (u >> 6) & 31, k16 = u & 63;
            const unsigned short* src = (arr ? hlo_w : hhi_w) + (size_t)b * HIDDEN + k16 * 8;
            int4 v = *(const int4*)src;
            char* base = (char*)(arr ? hs_lo : hs_hi);
            *(int4*)(base + ((b * 1024 + k16 * 16) ^ ((b & 7) << 4))) = v;
        }
        __syncthreads();

        const int w = tid >> 6, lane = tid & 63, row = lane & 15, kg = lane >> 4;
        const int vwave = blk * VB + w * 16;
        const unsigned short* wh = Whi + (size_t)(vwave + row) * HIDDEN + kg * 8;
        const unsigned short* wl = Wlo + (size_t)(vwave + row) * HIDDEN + kg * 8;

        f32x4 acc0 = {0.f, 0.f, 0.f, 0.f};   // b = row
        f32x4 acc1 = {0.f, 0.f, 0.f, 0.f};   // b = row + 16

        bf16x8 whb[4], wlb[4];
        #pragma unroll
        for (int p = 0; p < 4; ++p) {
            whb[p] = *(const bf16x8*)(wh + p * 32);
            wlb[p] = *(const bf16x8*)(wl + p * 32);
        }
        #pragma unroll
        for (int c = 0; c < 16; ++c) {
            bf16x8 cwh = whb[c & 3], cwl = wlb[c & 3];
            bf16x8 hh0 = *HPTR(hs_hi, row, c),      hh1 = *HPTR(hs_hi, row + 16, c);
            bf16x8 hl0 = *HPTR(hs_lo, row, c),      hl1 = *HPTR(hs_lo, row + 16, c);
            if (c + 4 < 16) {
                whb[c & 3] = *(const bf16x8*)(wh + (c + 4) * 32);
                wlb[c & 3] = *(const bf16x8*)(wl + (c + 4) * 32);
            }
            acc0 = MFMA(cwh, hh0, acc0); acc1 = MFMA(cwh, hh1, acc1);
            acc0 = MFMA(cwl, hh0, acc0); acc1 = MFMA(cwl, hh1, acc1);
            acc0 = MFMA(cwh, hl0, acc0); acc1 = MFMA(cwh, hl1, acc1);
        }

        const int v4 = vwave + kg * 4;        // D: row(m) = kg*4 + reg -> v; col(n) = row -> b
        f32x4 bias = *(const f32x4*)(b_fc + v4);
        f32x4 st0, st1;
        unsigned long long best0 = 0ull, best1 = 0ull;
        #pragma unroll
        for (int jj = 0; jj < 4; ++jj) {
            st0[jj] = acc0[jj] + bias[jj];
            st1[jj] = acc1[jj] + bias[jj];
            unsigned long long e0 = ((unsigned long long)f32_ordered_key(st0[jj]) << 32)
                                  | (unsigned long long)(~(unsigned int)(v4 + jj));
            unsigned long long e1 = ((unsigned long long)f32_ordered_key(st1[jj]) << 32)
                                  | (unsigned long long)(~(unsigned int)(v4 + jj));
            if (e0 > best0) best0 = e0;
            if (e1 > best1) best1 = e1;
        }
        __builtin_nontemporal_store(st0, (f32x4*)(out + ((size_t)row * MAXLEN + t) * VOCAB + v4));
        __builtin_nontemporal_store(st1, (f32x4*)(out + ((size_t)(row + 16) * MAXLEN + t) * VOCAB + v4));

        #pragma unroll
        for (int sft = 16; sft <= 32; sft <<= 1) {
            unsigned long long o0 = __shfl_xor(best0, sft, 64);
            unsigned long long o1 = __shfl_xor(best1, sft, 64);
            if (o0 > best0) best0 = o0;
            if (o1 > best1) best1 = o1;
        }
        if (kg == 0) { red[w][row] = best0; red[w][row + 16] = best1; }
        __syncthreads();
        if (tid < BATCH) {
            unsigned long long m = red[0][tid];
            #pragma unroll
            for (int ww = 1; ww < 8; ++ww) if (red[ww][tid] > m) m = red[ww][tid];
            cand[(size_t)blk * BATCH + tid] = m;   // plain store; next dispatch reads it
        }
    }
}

extern "C" void kernel_launch(void* const* d_in, const int* in_sizes, int n_in,
                              void* d_out, int out_size, void* d_ws, size_t ws_size,
                              hipStream_t stream) {
    const float* embed = (const float*)d_in[1];
    const float* W_ih  = (const float*)d_in[2];
    const float* W_hh  = (const float*)d_in[3];
    const float* b_ih  = (const float*)d_in[4];
    const float* b_hh  = (const float*)d_in[5];
    const float* W_fc  = (const float*)d_in[6];
    const float* b_fc  = (const float*)d_in[7];
    float* out = (float*)d_out;

    char* ws = (char*)d_ws;
    float* c_buf = (float*)(ws + WS_C_OFF);
    unsigned short* h_hi = (unsigned short*)(ws + WS_HHI_OFF);   // [2][32][512]
    unsigned short* h_lo = (unsigned short*)(ws + WS_HLO_OFF);   // [2][32][512]
    unsigned long long* cand = (unsigned long long*)(ws + WS_CAND_OFF);
    unsigned* stepctr = (unsigned*)(ws + WS_CTR_OFF);
    unsigned short* W_hi = (unsigned short*)(ws + WS_WHI_OFF);
    unsigned short* W_lo = (unsigned short*)(ws + WS_WLO_OFF);

    hipMemsetAsync(d_ws, 0, WS_ZERO_BYTES, stream);
    split_w_kernel<<<2048, 256, 0, stream>>>(W_fc, W_hi, W_lo, VOCAB * HIDDEN / 4);

    for (int t = 0; t < MAXLEN; ++t) {
        fused_step_kernel<<<NBLK, 512, 0, stream>>>(
            embed, W_ih, W_hh, b_ih, b_hh, W_hi, W_lo, b_fc, out,
            h_hi, h_lo, c_buf, cand, stepctr, t);
    }
}